// Round 3
// baseline (2283.610 us; speedup 1.0000x reference)
//
#include <hip/hip_runtime.h>
#include <cstdint>

#define NITEMS   100000
#define BROWS    512
#define DDIM     64
#define S_BLOCKS 391        // prep norm-blocks (256 items each) -> wsAM4
#define AM4_N    (S_BLOCKS * 4)
#define SB_OUT   256        // MFMA path: per-row partial maxima count
#define NTILES   3125       // 100000 / 32, exact
#define NMFMA    1024       // MFMA blocks (256 xb * 4 rg)
#define NTFB     1000       // threefry blocks: 1000*256 thr * 200 items = 51.2M exact
#define TF_L     200        // items per thread
#define ACAP     32         // per-wave arena capacity (mean 15.8, +4sigma=32 -> rowbad)
#define CCAP     384        // per-row candidate list (mean 247, +8.7sigma)
#define FB_X     64         // fallback item-chunks (1568 items each)
#define FB_Y     8
#define FB_CHUNK 1568
#define OUT_FEAT 512
#define OUT_LOSS (512 + 512 * 64)
#define OUT_MSIM (OUT_LOSS + 1)

// Gumbel filter: g monotone in bits; bits >= T <=> g may exceed 6.0.
#define BITS_RAW_T 4284334592u
#define G_TE       6.001f

typedef __attribute__((ext_vector_type(8)))  short  bf16x8;
typedef __attribute__((ext_vector_type(16))) float  f32x16;
typedef unsigned long long u64;
typedef uint32_t u32;

#define ROTL(x, r) __builtin_amdgcn_alignbit((x), (x), 32u - (r))

// ---------------- Threefry-2x32-20, key=(0,42). VERIFIED R4 (absmax 0.0):
// partitionable scheme, counters (hi=0, lo=e), output = bits1 ^ bits2.
__device__ __forceinline__ u32 threefry_0_42_xor(u32 e) {
    const u32 K1 = 42u;
    const u32 K2 = 0x1BD11BDAu ^ 42u;   // K0 = 0
    u32 x0 = 0u;
    u32 x1 = e + K1;
#define TFR(r) { x0 += x1; x1 = ROTL(x1, r) ^ x0; }
    TFR(13u) TFR(15u) TFR(26u) TFR(6u)
    x0 += K1;  x1 += K2 + 1u;
    TFR(17u) TFR(29u) TFR(16u) TFR(24u)
    x0 += K2;  x1 += 2u;
    TFR(13u) TFR(15u) TFR(26u) TFR(6u)
    x1 += K1 + 3u;
    TFR(17u) TFR(29u) TFR(16u) TFR(24u)
    x0 += K1;  x1 += K2 + 4u;
    TFR(13u) TFR(15u) TFR(26u) TFR(6u)
    x0 += K2;  x1 += 5u;
#undef TFR
    return x0 ^ x1;
}

// Four independent chains interleaved: ILP 4 on the serial threefry chain.
// Bit-identical to threefry_0_42_xor per chain by construction.
__device__ __forceinline__ void threefry_quad(u32 e0, u32 e1, u32 e2, u32 e3,
                                              u32& r0, u32& r1, u32& r2, u32& r3) {
    const u32 K1 = 42u;
    const u32 K2 = 0x1BD11BDAu ^ 42u;
    u32 a0 = 0u, a1 = e0 + K1;
    u32 b0 = 0u, b1 = e1 + K1;
    u32 c0 = 0u, c1 = e2 + K1;
    u32 d0 = 0u, d1 = e3 + K1;
#define TFR4(r) { a0 += a1; b0 += b1; c0 += c1; d0 += d1; \
                  a1 = ROTL(a1, r) ^ a0; b1 = ROTL(b1, r) ^ b0; \
                  c1 = ROTL(c1, r) ^ c0; d1 = ROTL(d1, r) ^ d0; }
    TFR4(13u) TFR4(15u) TFR4(26u) TFR4(6u)
    a0 += K1; a1 += K2 + 1u;  b0 += K1; b1 += K2 + 1u;
    c0 += K1; c1 += K2 + 1u;  d0 += K1; d1 += K2 + 1u;
    TFR4(17u) TFR4(29u) TFR4(16u) TFR4(24u)
    a0 += K2; a1 += 2u;       b0 += K2; b1 += 2u;
    c0 += K2; c1 += 2u;       d0 += K2; d1 += 2u;
    TFR4(13u) TFR4(15u) TFR4(26u) TFR4(6u)
    a1 += K1 + 3u;            b1 += K1 + 3u;
    c1 += K1 + 3u;            d1 += K1 + 3u;
    TFR4(17u) TFR4(29u) TFR4(16u) TFR4(24u)
    a0 += K1; a1 += K2 + 4u;  b0 += K1; b1 += K2 + 4u;
    c0 += K1; c1 += K2 + 4u;  d0 += K1; d1 += K2 + 4u;
    TFR4(13u) TFR4(15u) TFR4(26u) TFR4(6u)
    a0 += K2; a1 += 5u;       b0 += K2; b1 += 5u;
    c0 += K2; c1 += 5u;       d0 += K2; d1 += 5u;
#undef TFR4
    r0 = a0 ^ a1; r1 = b0 ^ b1; r2 = c0 ^ c1; r3 = d0 ^ d1;
}

__device__ __forceinline__ float gumbel_from_bits(u32 b) {   // precise logf REQUIRED
    float f = __uint_as_float((b >> 9) | 0x3F800000u) - 1.0f;
    f = fmaxf(f, 1.17549435e-38f);
    return -logf(-logf(f));
}
__device__ __forceinline__ u32 order_map(float v) {
    u32 x = __float_as_uint(v);
    return (x & 0x80000000u) ? ~x : (x | 0x80000000u);
}
__device__ __forceinline__ float unpack_val(u64 p) {
    u32 x = (u32)(p >> 32);
    u32 f = (x & 0x80000000u) ? (x & 0x7FFFFFFFu) : ~x;
    return __uint_as_float(f);
}
__device__ __forceinline__ short f32_to_bf16_rne(float f) {
    u32 b = __float_as_uint(f);
    u32 r = (b + 0x7FFFu + ((b >> 16) & 1u)) >> 16;
    return (short)r;
}

// ---------------- K1: prep = uif GEMM (W^T in LDS) + norms + zero state ----
__global__ void prep_kernel(const float* __restrict__ UF, const float* __restrict__ W,
                            const float* __restrict__ bias, const float* __restrict__ A,
                            float* __restrict__ uif, float* __restrict__ unorm,
                            float* __restrict__ wsAM4, int* __restrict__ cnt,
                            int* __restrict__ done, int* __restrict__ ccnt,
                            int* __restrict__ rowbad, float* __restrict__ out) {
    const int t = threadIdx.x, b = blockIdx.x;
    if (b == 0) {
        if (t == 0) { *cnt = 0; out[OUT_LOSS] = 0.f; out[OUT_MSIM] = 0.f; }
        done[t] = 0;   done[t + 256] = 0;
        ccnt[t] = 0;   ccnt[t + 256] = 0;
        rowbad[t] = 0; rowbad[t + 256] = 0;
    }
    if (b < 128) {
        __shared__ float Wt[128 * 65];
        for (int i = t; i < 8192; i += 256) {
            int d = i >> 7, k = i & 127;
            Wt[k * 65 + d] = W[i];
        }
        __syncthreads();
        const int row = b * 4 + (t >> 6);
        const int d   = t & 63;
        const float* u = UF + row * 128;
        float s = 0.f;
#pragma unroll 4
        for (int k = 0; k < 128; k++) s = fmaf(u[k], Wt[k * 65 + d], s);
        s += bias[d];
        uif[row * 64 + d] = s;
        float q = s * s;
#pragma unroll
        for (int o = 32; o >= 1; o >>= 1) q += __shfl_xor(q, o);
        if (d == 0) unorm[row] = sqrtf(q);
    } else {
        const int item = (b - 128) * 256 + t;
        float q = 0.f;
        if (item < NITEMS) {
            const float4* r = (const float4*)(A + (size_t)item * DDIM);
#pragma unroll
            for (int k = 0; k < 16; k++) {
                float4 x = r[k];
                q = fmaf(x.x, x.x, q); q = fmaf(x.y, x.y, q);
                q = fmaf(x.z, x.z, q); q = fmaf(x.w, x.w, q);
            }
        }
        float n = sqrtf(q);
#pragma unroll
        for (int o = 32; o >= 1; o >>= 1) n = fmaxf(n, __shfl_xor(n, o));
        if ((t & 63) == 0) wsAM4[(b - 128) * 4 + (t >> 6)] = n;
    }
}

// ---------------- K2 (fused): TF filter blocks + MFMA row-max blocks -------
// TF blocks: pure threefry stream, no LDS/barriers; SALU ballot-push into
// per-wave arenas (fire-and-forget stores, NO atomic round-trip).
// MFMA blocks: R1-verified tile geometry, single-term bf16 -> per-row max.
__global__ __launch_bounds__(256, 6) void phase1f_kernel(
        const float* __restrict__ A, const float* __restrict__ uif,
        float* __restrict__ wsB, u64* __restrict__ arena,
        u32* __restrict__ acnt, int* __restrict__ rowbad) {
    __shared__ bf16x8 sh_ah[4 * 64];
    const int bid  = blockIdx.x;
    const int tid  = threadIdx.x;
    const int lane = tid & 63;
    const int wv   = tid >> 6;

    // role map: bid<2000: even->MFMA(bid/2), odd->TF(bid/2); 2000+: MFMA tail
    int mfma_id = -1, tf_id = -1;
    if (bid < 2 * NTFB) { if (bid & 1) tf_id = bid >> 1; else mfma_id = bid >> 1; }
    else mfma_id = NTFB + (bid - 2 * NTFB);

    if (tf_id >= 0) {
        // ---------------- threefry filter path ----------------
        const int gid = tf_id * 256 + tid;
        u32 e = (u32)gid * (u32)TF_L;
        const u64 lanelt = (lane == 0) ? 0ull : (~0ull >> (64 - lane));
        u32 cq = 0;
        const int wid = tf_id * 4 + wv;
        u64* __restrict__ myA = arena + (size_t)wid * ACAP;
        for (int k = 0; k < TF_L / 4; k++) {
            u32 r0, r1, r2, r3;
            threefry_quad(e, e + 1u, e + 2u, e + 3u, r0, r1, r2, r3);
            bool v0 = r0 >= BITS_RAW_T, v1 = r1 >= BITS_RAW_T;
            bool v2 = r2 >= BITS_RAW_T, v3 = r3 >= BITS_RAW_T;
            u64 m0 = __ballot(v0), m1 = __ballot(v1);
            u64 m2 = __ballot(v2), m3 = __ballot(v3);
            if (v0) { u32 ix = cq + (u32)__popcll(m0 & lanelt);
                      if (ix < ACAP) myA[ix] = ((u64)r0 << 32) | (u64)e; }
            cq += (u32)__popcll(m0);
            if (v1) { u32 ix = cq + (u32)__popcll(m1 & lanelt);
                      if (ix < ACAP) myA[ix] = ((u64)r1 << 32) | (u64)(e + 1u); }
            cq += (u32)__popcll(m1);
            if (v2) { u32 ix = cq + (u32)__popcll(m2 & lanelt);
                      if (ix < ACAP) myA[ix] = ((u64)r2 << 32) | (u64)(e + 2u); }
            cq += (u32)__popcll(m2);
            if (v3) { u32 ix = cq + (u32)__popcll(m3 & lanelt);
                      if (ix < ACAP) myA[ix] = ((u64)r3 << 32) | (u64)(e + 3u); }
            cq += (u32)__popcll(m3);
            e += 4u;
        }
        if (lane == 0) {
            acnt[wid] = cq < (u32)ACAP ? cq : (u32)ACAP;
            if (cq > (u32)ACAP) {            // astronomically rare; safe path
                u32 es = (u32)(tf_id * 256 + wv * 64) * (u32)TF_L;
                rowbad[es / 100000u] = 1;
                rowbad[(es + (u32)(64 * TF_L) - 1u) / 100000u] = 1;
            }
        }
        return;
    }

    // ---------------- MFMA row-max path (single-term bf16) ----------------
    const int xb = mfma_id & 255;
    const int rg = mfma_id >> 8;
    const int row   = rg * 128 + wv * 32 + (lane & 31);
    const int khalf = (lane >> 5) * 8;

    bf16x8 uh[4];
#pragma unroll
    for (int s = 0; s < 4; s++) {
        const float* src = uif + row * 64 + khalf + 16 * s;
        float4 v0 = *(const float4*)src;
        float4 v1 = *(const float4*)(src + 4);
        float vv[8] = {v0.x, v0.y, v0.z, v0.w, v1.x, v1.y, v1.z, v1.w};
        bf16x8 h;
#pragma unroll
        for (int j = 0; j < 8; j++) h[j] = f32_to_bf16_rne(vv[j]);
        uh[s] = h;
    }

    float sm = -3.0e38f;
    const int s_i   = tid & 31;
    const int s_c   = tid >> 5;
    const int s_dst = (s_c >> 1) * 64 + s_i + 32 * (s_c & 1);   // R7-verified map
    const float* s_srcbase = A + (size_t)s_i * 64 + 8 * s_c;

    int t_idx = xb;
    float4 p0 = *(const float4*)(s_srcbase + (size_t)t_idx * 2048);
    float4 p1 = *(const float4*)(s_srcbase + (size_t)t_idx * 2048 + 4);

    while (t_idx < NTILES) {
        bf16x8 h;
        {
            float vv[8] = {p0.x, p0.y, p0.z, p0.w, p1.x, p1.y, p1.z, p1.w};
#pragma unroll
            for (int j = 0; j < 8; j++) h[j] = f32_to_bf16_rne(vv[j]);
        }
        __syncthreads();
        sh_ah[s_dst] = h;
        __syncthreads();
        t_idx += SB_OUT;
        if (t_idx < NTILES) {
            const float* src = s_srcbase + (size_t)t_idx * 2048;
            p0 = *(const float4*)src;
            p1 = *(const float4*)(src + 4);
        }

        f32x16 acc;
#pragma unroll
        for (int z = 0; z < 16; z++) acc[z] = 0.0f;
#pragma unroll
        for (int s = 0; s < 4; s++)
            acc = __builtin_amdgcn_mfma_f32_32x32x16_bf16(sh_ah[s * 64 + lane], uh[s],
                                                          acc, 0, 0, 0);
#pragma unroll
        for (int i = 0; i < 16; i++) sm = fmaxf(sm, acc[i]);
    }

    sm = fmaxf(sm, __shfl_xor(sm, 32));
    if (lane < 32) wsB[(size_t)row * SB_OUT + xb] = sm;
}

// ---------------- K3: compact per-wave arenas -> per-row candidate lists ---
__global__ void compact_kernel(const u64* __restrict__ arena, const u32* __restrict__ acnt,
                               u64* __restrict__ cand, int* __restrict__ ccnt,
                               int* __restrict__ rowbad) {
    const int tid = threadIdx.x, lane = tid & 63, wv = tid >> 6;
    const int w = blockIdx.x * 4 + wv;            // 0..999
#pragma unroll
    for (int q = 0; q < 4; q++) {
        const int a = w * 4 + q;                  // 0..3999
        u32 n = acnt[a];
        if ((u32)lane < n) {
            u64 ent = arena[(size_t)a * ACAP + lane];
            u32 e = (u32)ent;
            u32 row = (u32)(((u64)e * 5629499535ull) >> 49);   // exact /100000
            u32 item = e - row * 100000u;
            int slot = atomicAdd(&ccnt[row], 1);
            if (slot < CCAP) cand[(size_t)row * CCAP + slot] =
                                 (ent & 0xFFFFFFFF00000000ull) | (u64)item;
            else rowbad[row] = 1;
        }
    }
}

// ---------------- K4: merge: exact candidate dots + certify ---------------
// Candidates carry exact f32 scores (R5-verified op order == reference) =>
// no top-2 gap needed: cert is just t1 > smb + E1 + 6.001 (non-cand g<=6).
__global__ void merge_kernel(const float* __restrict__ wsB, const float* __restrict__ wsAM4,
                             const float* __restrict__ unorm, const u64* __restrict__ cand,
                             const int* __restrict__ ccnt, const int* __restrict__ rowbad,
                             const float* __restrict__ uif, const float* __restrict__ A,
                             const int* __restrict__ need_replace,
                             u64* __restrict__ packed, int* __restrict__ rowlist,
                             int* __restrict__ cnt, float* __restrict__ out) {
    const int row = blockIdx.x, t = threadIdx.x;     // 64 threads = 1 wave
    __shared__ float Us[64];
    Us[t] = uif[row * 64 + t];
    __syncthreads();

    float am = 0.f;
    for (int i = t; i < AM4_N; i += 64) am = fmaxf(am, wsAM4[i]);
    float smb = -3.0e38f;
    for (int i = t; i < SB_OUT; i += 64) smb = fmaxf(smb, wsB[(size_t)row * SB_OUT + i]);

    const int ncand = ccnt[row];
    const bool bad = (rowbad[row] != 0) || (ncand > CCAP);
    const int n = ncand < CCAP ? ncand : CCAP;

    u64 pk = 0ull;
    for (int j = t; j < n; j += 64) {
        u64 ent = cand[(size_t)row * CCAP + j];
        u32 item = (u32)ent;
        float g = gumbel_from_bits((u32)(ent >> 32));
        const float4* a4 = (const float4*)(A + (size_t)item * DDIM);
        float s0 = 0.f, s1 = 0.f;
#pragma unroll
        for (int k = 0; k < 16; k += 2) {     // R5-verified op order (exact)
            float4 x = a4[k];
            float4 y = a4[k + 1];
            s0 = fmaf(x.x, Us[4*k    ], s0);
            s0 = fmaf(x.y, Us[4*k + 1], s0);
            s0 = fmaf(x.z, Us[4*k + 2], s0);
            s0 = fmaf(x.w, Us[4*k + 3], s0);
            s1 = fmaf(y.x, Us[4*k + 4], s1);
            s1 = fmaf(y.y, Us[4*k + 5], s1);
            s1 = fmaf(y.z, Us[4*k + 6], s1);
            s1 = fmaf(y.w, Us[4*k + 7], s1);
        }
        float v = (s0 + s1) + g;
        u64 c = ((u64)order_map(v) << 32) | (u32)(~item);
        pk = (c > pk) ? c : pk;
    }
#pragma unroll
    for (int off = 1; off < 64; off <<= 1) {
        u64 o = __shfl_xor(pk, off);
        pk = (o > pk) ? o : pk;
        am  = fmaxf(am,  __shfl_xor(am,  off));
        smb = fmaxf(smb, __shfl_xor(smb, off));
    }
    // 1-term bf16 margin: |s_f32 - s_bf16| <= 2^-8*|a||u| (+accum slack)
    const float E1 = 8.0e-3f * unorm[row] * am + 1.0e-4f;
    const float v1 = unpack_val(pk);        // NaN when pk==0 -> cert false
    if (!bad && (v1 > smb + E1 + G_TE)) {
        const int idx = (int)(~(u32)(pk & 0xFFFFFFFFull));
        float fr = A[(size_t)idx * DDIM + t];
        out[OUT_FEAT + row * DDIM + t] = fr;
        int   item = need_replace[2 * row + 1];
        float fa   = A[(size_t)item * DDIM + t];
        float dot = fa * fr, na2 = fa * fa, nb2 = fr * fr;
#pragma unroll
        for (int o = 32; o >= 1; o >>= 1) {
            dot += __shfl_down(dot, o);
            na2 += __shfl_down(na2, o);
            nb2 += __shfl_down(nb2, o);
        }
        if (t == 0) {
            out[row] = (float)idx;
            float denom = fmaxf(sqrtf(na2) * sqrtf(nb2), 1e-6f);
            float sim = (dot / denom + 1.0f) * 0.5f;
            float d = sim - 0.5f;
            atomicAdd(&out[OUT_LOSS], d * d * (1.0f / 512.0f));
            atomicAdd(&out[OUT_MSIM], sim * (1.0f / 512.0f));
        }
    } else if (t == 0) {
        packed[row] = 0ull;
        rowlist[atomicAdd(cnt, 1)] = row;
    }
}

// ---------------- K5: exact f32 fallback (512 blocks); last block resolves -
__global__ void fallback_kernel(const float* __restrict__ A, const float* __restrict__ uif,
                                const int* __restrict__ rowlist, const int* __restrict__ cnt,
                                const int* __restrict__ need_replace,
                                u64* __restrict__ packed, int* __restrict__ done,
                                float* __restrict__ out) {
    __shared__ float Us[64];
    __shared__ int   sh_last;
    const int t  = threadIdx.x;          // 0..255
    const int xb = blockIdx.x;           // 0..63
    const int total = *cnt;
    const int iend = min((xb + 1) * FB_CHUNK, NITEMS);

    for (int li = blockIdx.y; li < total; li += FB_Y) {
        const int row = rowlist[li];
        __syncthreads();
        if (t < 64) Us[t] = uif[row * 64 + t];
        __syncthreads();
        u64 pk = 0ull;
        for (int item = xb * FB_CHUNK + t; item < iend; item += 256) {
            u32 rb  = threefry_0_42_xor((u32)row * (u32)NITEMS + (u32)item);
            float g = gumbel_from_bits(rb);
            const float4* a4 = (const float4*)(A + (size_t)item * DDIM);
            float s0 = 0.f, s1 = 0.f;
#pragma unroll
            for (int k = 0; k < 16; k += 2) {     // R5-verified op order
                float4 x = a4[k];
                float4 y = a4[k + 1];
                s0 = fmaf(x.x, Us[4*k    ], s0);
                s0 = fmaf(x.y, Us[4*k + 1], s0);
                s0 = fmaf(x.z, Us[4*k + 2], s0);
                s0 = fmaf(x.w, Us[4*k + 3], s0);
                s1 = fmaf(y.x, Us[4*k + 4], s1);
                s1 = fmaf(y.y, Us[4*k + 5], s1);
                s1 = fmaf(y.z, Us[4*k + 6], s1);
                s1 = fmaf(y.w, Us[4*k + 7], s1);
            }
            float v = (s0 + s1) + g;
            u64 c = ((u64)order_map(v) << 32) | (u32)(~(u32)item);
            pk = (c > pk) ? c : pk;
        }
#pragma unroll
        for (int off = 1; off < 64; off <<= 1) {
            u64 o = __shfl_xor(pk, off);
            pk = (o > pk) ? o : pk;
        }
        if ((t & 63) == 0) atomicMax(&packed[row], pk);
        __syncthreads();
        if (t == 0) {
            __threadfence();
            sh_last = (atomicAdd(&done[li], 1) == FB_X - 1) ? 1 : 0;
        }
        __syncthreads();
        if (sh_last && t < 64) {               // last contributor resolves row
            u64 fin = atomicMax(&packed[row], 0ull);   // coherent read
            const int idx = (int)(~(u32)(fin & 0xFFFFFFFFull));
            float fr = A[(size_t)idx * DDIM + t];
            out[OUT_FEAT + row * DDIM + t] = fr;
            int   item = need_replace[2 * row + 1];
            float fa   = A[(size_t)item * DDIM + t];
            float dot = fa * fr, na2 = fa * fa, nb2 = fr * fr;
#pragma unroll
            for (int o = 32; o >= 1; o >>= 1) {
                dot += __shfl_down(dot, o);
                na2 += __shfl_down(na2, o);
                nb2 += __shfl_down(nb2, o);
            }
            if (t == 0) {
                out[row] = (float)idx;
                float denom = fmaxf(sqrtf(na2) * sqrtf(nb2), 1e-6f);
                float sim = (dot / denom + 1.0f) * 0.5f;
                float d = sim - 0.5f;
                atomicAdd(&out[OUT_LOSS], d * d * (1.0f / 512.0f));
                atomicAdd(&out[OUT_MSIM], sim * (1.0f / 512.0f));
            }
        }
        __syncthreads();
    }
}

extern "C" void kernel_launch(void* const* d_in, const int* in_sizes, int n_in,
                              void* d_out, int out_size, void* d_ws, size_t ws_size,
                              hipStream_t stream) {
    (void)in_sizes; (void)n_in; (void)out_size; (void)ws_size;
    const int*   need_replace = (const int*)d_in[0];
    const float* UF           = (const float*)d_in[1];
    const float* A            = (const float*)d_in[2];
    const float* W            = (const float*)d_in[3];
    const float* bias         = (const float*)d_in[4];
    float* out = (float*)d_out;

    char* ws = (char*)d_ws;                              // ~3.29 MB total
    u64*   arena   = (u64*)  (ws);                       // 4000*32*8 = 1024000
    u64*   cand    = (u64*)  (ws + 1024000);             // 512*384*8 = 1572864
    float* wsB     = (float*)(ws + 2596864);             // 512*256*4 = 524288
    float* uif     = (float*)(ws + 3121152);             // 131072
    u64*   packed  = (u64*)  (ws + 3252224);             // 4096
    u32*   acnt    = (u32*)  (ws + 3256320);             // 16000
    float* unorm   = (float*)(ws + 3272320);             // 2048
    float* wsAM4   = (float*)(ws + 3274368);             // 6256
    int*   ccnt    = (int*)  (ws + 3280624);             // 2048
    int*   rowbad  = (int*)  (ws + 3282672);             // 2048
    int*   rowlist = (int*)  (ws + 3284720);             // 2048
    int*   cnt     = (int*)  (ws + 3286768);             // 4
    int*   done    = (int*)  (ws + 3286772);             // 2048

    prep_kernel<<<519, 256, 0, stream>>>(UF, W, bias, A, uif, unorm, wsAM4, cnt, done,
                                         ccnt, rowbad, out);
    phase1f_kernel<<<2 * NTFB + (NMFMA - NTFB), 256, 0, stream>>>(A, uif, wsB, arena,
                                                                  acnt, rowbad);
    compact_kernel<<<250, 256, 0, stream>>>(arena, acnt, cand, ccnt, rowbad);
    merge_kernel<<<BROWS, 64, 0, stream>>>(wsB, wsAM4, unorm, cand, ccnt, rowbad,
                                           uif, A, need_replace, packed, rowlist, cnt, out);
    fallback_kernel<<<dim3(FB_X, FB_Y), 256, 0, stream>>>(A, uif, rowlist, cnt,
                                                          need_replace, packed, done, out);
}

// Round 5
// 434.125 us; speedup vs baseline: 5.2603x; 5.2603x over previous
//
#include <hip/hip_runtime.h>
#include <cstdint>

#define NITEMS   100000
#define BROWS    512
#define DDIM     64
#define S_BLOCKS 391        // prep norm-blocks (256 items each) -> wsAM4
#define AM4_N    (S_BLOCKS * 4)
#define SB_OUT   256        // MFMA path: xb count (tile stride)
#define NTILES   3125       // 100000 / 32, exact
#define NROLE    1024       // blocks per role (TF / MFMA)
#define TF_L     196        // items per TF thread (1024*256*196 >= 51.2M)
#define EMAX     51200000u  // 512 rows * 100000 items
#define ACAP     64         // per-wave arena cap (mean 31.1, +5.9 sigma)
#define CCAP     384        // per-row candidate list (mean 247.5, +8.7 sigma)
#define FB_X     64         // fallback item-chunks (1568 items each)
#define FB_Y     8
#define FB_CHUNK 1568
#define OUT_FEAT 512
#define OUT_LOSS (512 + 512 * 64)
#define OUT_MSIM (OUT_LOSS + 1)

// Gumbel filter: g monotone in bits; bits >= T <=> g may exceed 6.0.
#define BITS_RAW_T 4284334592u
#define G_TE       6.001f

typedef __attribute__((ext_vector_type(8)))  short  bf16x8;
typedef __attribute__((ext_vector_type(16))) float  f32x16;
typedef unsigned long long u64;
typedef uint32_t u32;

#define ROTL(x, r) __builtin_amdgcn_alignbit((x), (x), 32u - (r))

// ---------------- Threefry-2x32-20, key=(0,42). VERIFIED R4 (absmax 0.0):
// partitionable scheme, counters (hi=0, lo=e), output = bits1 ^ bits2.
__device__ __forceinline__ u32 threefry_0_42_xor(u32 e) {
    const u32 K1 = 42u;
    const u32 K2 = 0x1BD11BDAu ^ 42u;   // K0 = 0
    u32 x0 = 0u;
    u32 x1 = e + K1;
#define TFR(r) { x0 += x1; x1 = ROTL(x1, r) ^ x0; }
    TFR(13u) TFR(15u) TFR(26u) TFR(6u)
    x0 += K1;  x1 += K2 + 1u;
    TFR(17u) TFR(29u) TFR(16u) TFR(24u)
    x0 += K2;  x1 += 2u;
    TFR(13u) TFR(15u) TFR(26u) TFR(6u)
    x1 += K1 + 3u;
    TFR(17u) TFR(29u) TFR(16u) TFR(24u)
    x0 += K1;  x1 += K2 + 4u;
    TFR(13u) TFR(15u) TFR(26u) TFR(6u)
    x0 += K2;  x1 += 5u;
#undef TFR
    return x0 ^ x1;
}

// Four independent chains interleaved: ILP 4 on the serial threefry chain.
// Bit-identical to threefry_0_42_xor per chain by construction.
__device__ __forceinline__ void threefry_quad(u32 e0, u32 e1, u32 e2, u32 e3,
                                              u32& r0, u32& r1, u32& r2, u32& r3) {
    const u32 K1 = 42u;
    const u32 K2 = 0x1BD11BDAu ^ 42u;
    u32 a0 = 0u, a1 = e0 + K1;
    u32 b0 = 0u, b1 = e1 + K1;
    u32 c0 = 0u, c1 = e2 + K1;
    u32 d0 = 0u, d1 = e3 + K1;
#define TFR4(r) { a0 += a1; b0 += b1; c0 += c1; d0 += d1; \
                  a1 = ROTL(a1, r) ^ a0; b1 = ROTL(b1, r) ^ b0; \
                  c1 = ROTL(c1, r) ^ c0; d1 = ROTL(d1, r) ^ d0; }
    TFR4(13u) TFR4(15u) TFR4(26u) TFR4(6u)
    a0 += K1; a1 += K2 + 1u;  b0 += K1; b1 += K2 + 1u;
    c0 += K1; c1 += K2 + 1u;  d0 += K1; d1 += K2 + 1u;
    TFR4(17u) TFR4(29u) TFR4(16u) TFR4(24u)
    a0 += K2; a1 += 2u;       b0 += K2; b1 += 2u;
    c0 += K2; c1 += 2u;       d0 += K2; d1 += 2u;
    TFR4(13u) TFR4(15u) TFR4(26u) TFR4(6u)
    a1 += K1 + 3u;            b1 += K1 + 3u;
    c1 += K1 + 3u;            d1 += K1 + 3u;
    TFR4(17u) TFR4(29u) TFR4(16u) TFR4(24u)
    a0 += K1; a1 += K2 + 4u;  b0 += K1; b1 += K2 + 4u;
    c0 += K1; c1 += K2 + 4u;  d0 += K1; d1 += K2 + 4u;
    TFR4(13u) TFR4(15u) TFR4(26u) TFR4(6u)
    a0 += K2; a1 += 5u;       b0 += K2; b1 += 5u;
    c0 += K2; c1 += 5u;       d0 += K2; d1 += 5u;
#undef TFR4
    r0 = a0 ^ a1; r1 = b0 ^ b1; r2 = c0 ^ c1; r3 = d0 ^ d1;
}

__device__ __forceinline__ float gumbel_from_bits(u32 b) {   // precise logf REQUIRED
    float f = __uint_as_float((b >> 9) | 0x3F800000u) - 1.0f;
    f = fmaxf(f, 1.17549435e-38f);
    return -logf(-logf(f));
}
__device__ __forceinline__ u32 order_map(float v) {
    u32 x = __float_as_uint(v);
    return (x & 0x80000000u) ? ~x : (x | 0x80000000u);
}
__device__ __forceinline__ float unpack_val(u64 p) {
    u32 x = (u32)(p >> 32);
    u32 f = (x & 0x80000000u) ? (x & 0x7FFFFFFFu) : ~x;
    return __uint_as_float(f);
}
__device__ __forceinline__ float unpack_om(u32 x) {
    u32 f = (x & 0x80000000u) ? (x & 0x7FFFFFFFu) : ~x;
    return __uint_as_float(f);
}
__device__ __forceinline__ short f32_to_bf16_rne(float f) {
    u32 b = __float_as_uint(f);
    u32 r = (b + 0x7FFFu + ((b >> 16) & 1u)) >> 16;
    return (short)r;
}

// ---------------- K1: prep = uif GEMM (W^T in LDS) + norms + zero state ----
__global__ void prep_kernel(const float* __restrict__ UF, const float* __restrict__ W,
                            const float* __restrict__ bias, const float* __restrict__ A,
                            float* __restrict__ uif, float* __restrict__ unorm,
                            float* __restrict__ wsAM4, int* __restrict__ cnt,
                            int* __restrict__ done, int* __restrict__ ccnt,
                            int* __restrict__ rowbad, u32* __restrict__ wsBm,
                            float* __restrict__ out) {
    const int t = threadIdx.x, b = blockIdx.x;
    if (b == 0) {
        if (t == 0) { *cnt = 0; out[OUT_LOSS] = 0.f; out[OUT_MSIM] = 0.f; }
        done[t] = 0;   done[t + 256] = 0;
        ccnt[t] = 0;   ccnt[t + 256] = 0;
        rowbad[t] = 0; rowbad[t + 256] = 0;
        wsBm[t] = 0u;  wsBm[t + 256] = 0u;
    }
    if (b < 128) {
        __shared__ float Wt[128 * 65];
        for (int i = t; i < 8192; i += 256) {
            int d = i >> 7, k = i & 127;
            Wt[k * 65 + d] = W[i];
        }
        __syncthreads();
        const int row = b * 4 + (t >> 6);
        const int d   = t & 63;
        const float* u = UF + row * 128;
        float s = 0.f;
#pragma unroll 4
        for (int k = 0; k < 128; k++) s = fmaf(u[k], Wt[k * 65 + d], s);
        s += bias[d];
        uif[row * 64 + d] = s;
        float q = s * s;
#pragma unroll
        for (int o = 32; o >= 1; o >>= 1) q += __shfl_xor(q, o);
        if (d == 0) unorm[row] = sqrtf(q);
    } else {
        const int item = (b - 128) * 256 + t;
        float q = 0.f;
        if (item < NITEMS) {
            const float4* r = (const float4*)(A + (size_t)item * DDIM);
#pragma unroll
            for (int k = 0; k < 16; k++) {
                float4 x = r[k];
                q = fmaf(x.x, x.x, q); q = fmaf(x.y, x.y, q);
                q = fmaf(x.z, x.z, q); q = fmaf(x.w, x.w, q);
            }
        }
        float n = sqrtf(q);
#pragma unroll
        for (int o = 32; o >= 1; o >>= 1) n = fmaxf(n, __shfl_xor(n, o));
        if ((t & 63) == 0) wsAM4[(b - 128) * 4 + (t >> 6)] = n;
    }
}

// ---------------- K2 (fused): TF filter blocks + MFMA row-max blocks -------
// Role map in GROUPS OF 8 so that bid%8->XCD round-robin gives every XCD an
// alternating TF/MFMA mix (R3 defect: bid&1 role + bid%8 XCD = segregated
// XCDs). grid 2048 @ launch_bounds(256,8) = exactly 8 blocks/CU, one round.
// TF blocks: pure threefry stream, ballot-compacted fire-and-forget pushes.
// MFMA blocks: single-term bf16 row-max, same-xb pairs land on same XCD.
__global__ __launch_bounds__(256, 8) void phase1f_kernel(
        const float* __restrict__ A, const float* __restrict__ uif,
        u32* __restrict__ wsBm, u64* __restrict__ arena,
        u32* __restrict__ acnt, int* __restrict__ rowbad) {
    __shared__ bf16x8 sh_ah[4 * 64];
    const int bid  = blockIdx.x;
    const int tid  = threadIdx.x;
    const int lane = tid & 63;
    const int wv   = tid >> 6;

    const int id8 = (bid >> 4) * 8 + (bid & 7);    // role-local id, 0..1023
    const bool is_tf = ((bid >> 3) & 1) != 0;

    if (is_tf) {
        // ---------------- threefry filter path ----------------
        const int gid = id8 * 256 + tid;
        u32 e = (u32)gid * (u32)TF_L;
        const u64 lanelt = (lane == 0) ? 0ull : (~0ull >> (64 - lane));
        u32 cq = 0;
        const int wid = id8 * 4 + wv;
        u64* __restrict__ myA = arena + (size_t)wid * ACAP;
        for (int k = 0; k < TF_L / 4; k++) {
            u32 r0, r1, r2, r3;
            threefry_quad(e, e + 1u, e + 2u, e + 3u, r0, r1, r2, r3);
            bool v0 = (r0 >= BITS_RAW_T) && (e       < EMAX);
            bool v1 = (r1 >= BITS_RAW_T) && (e + 1u  < EMAX);
            bool v2 = (r2 >= BITS_RAW_T) && (e + 2u  < EMAX);
            bool v3 = (r3 >= BITS_RAW_T) && (e + 3u  < EMAX);
            u64 m0 = __ballot(v0), m1 = __ballot(v1);
            u64 m2 = __ballot(v2), m3 = __ballot(v3);
            if (v0) { u32 ix = cq + (u32)__popcll(m0 & lanelt);
                      if (ix < ACAP) myA[ix] = ((u64)r0 << 32) | (u64)e; }
            cq += (u32)__popcll(m0);
            if (v1) { u32 ix = cq + (u32)__popcll(m1 & lanelt);
                      if (ix < ACAP) myA[ix] = ((u64)r1 << 32) | (u64)(e + 1u); }
            cq += (u32)__popcll(m1);
            if (v2) { u32 ix = cq + (u32)__popcll(m2 & lanelt);
                      if (ix < ACAP) myA[ix] = ((u64)r2 << 32) | (u64)(e + 2u); }
            cq += (u32)__popcll(m2);
            if (v3) { u32 ix = cq + (u32)__popcll(m3 & lanelt);
                      if (ix < ACAP) myA[ix] = ((u64)r3 << 32) | (u64)(e + 3u); }
            cq += (u32)__popcll(m3);
            e += 4u;
        }
        if (lane == 0) {
            acnt[wid] = cq < (u32)ACAP ? cq : (u32)ACAP;
            if (cq > (u32)ACAP) {            // ~1e-9/wave; safe path
                u32 es = (u32)(id8 * 256 + wv * 64) * (u32)TF_L;
                u32 ee = es + (u32)(64 * TF_L) - 1u;
                if (ee >= EMAX) ee = EMAX - 1u;
                if (es >= EMAX) es = EMAX - 1u;
                rowbad[es / 100000u] = 1;
                rowbad[ee / 100000u] = 1;
            }
        }
        return;
    }

    // ---------------- MFMA row-max path (single-term bf16) ----------------
    const int xb = id8 & 255;
    const int rg = id8 >> 8;
    const int row   = rg * 128 + wv * 32 + (lane & 31);
    const int khalf = (lane >> 5) * 8;

    bf16x8 uh[4];
#pragma unroll
    for (int s = 0; s < 4; s++) {
        const float* src = uif + row * 64 + khalf + 16 * s;
        float4 v0 = *(const float4*)src;
        float4 v1 = *(const float4*)(src + 4);
        float vv[8] = {v0.x, v0.y, v0.z, v0.w, v1.x, v1.y, v1.z, v1.w};
        bf16x8 h;
#pragma unroll
        for (int j = 0; j < 8; j++) h[j] = f32_to_bf16_rne(vv[j]);
        uh[s] = h;
    }

    float sm = -3.0e38f;
    const int s_i   = tid & 31;
    const int s_c   = tid >> 5;
    const int s_dst = (s_c >> 1) * 64 + s_i + 32 * (s_c & 1);   // R7-verified map
    const float* s_srcbase = A + (size_t)s_i * 64 + 8 * s_c;

    int t_idx = xb;
    float4 p0 = *(const float4*)(s_srcbase + (size_t)t_idx * 2048);
    float4 p1 = *(const float4*)(s_srcbase + (size_t)t_idx * 2048 + 4);

    while (t_idx < NTILES) {
        bf16x8 h;
        {
            float vv[8] = {p0.x, p0.y, p0.z, p0.w, p1.x, p1.y, p1.z, p1.w};
#pragma unroll
            for (int j = 0; j < 8; j++) h[j] = f32_to_bf16_rne(vv[j]);
        }
        __syncthreads();
        sh_ah[s_dst] = h;
        __syncthreads();
        t_idx += SB_OUT;
        if (t_idx < NTILES) {
            const float* src = s_srcbase + (size_t)t_idx * 2048;
            p0 = *(const float4*)src;
            p1 = *(const float4*)(src + 4);
        }

        f32x16 acc;
#pragma unroll
        for (int z = 0; z < 16; z++) acc[z] = 0.0f;
#pragma unroll
        for (int s = 0; s < 4; s++)
            acc = __builtin_amdgcn_mfma_f32_32x32x16_bf16(sh_ah[s * 64 + lane], uh[s],
                                                          acc, 0, 0, 0);
#pragma unroll
        for (int i = 0; i < 16; i++) sm = fmaxf(sm, acc[i]);
    }

    sm = fmaxf(sm, __shfl_xor(sm, 32));
    if (lane < 32) atomicMax(&wsBm[row], order_map(sm));
}

// ---------------- K3: compact per-wave arenas -> per-row candidate lists ---
__global__ void compact_kernel(const u64* __restrict__ arena, const u32* __restrict__ acnt,
                               u64* __restrict__ cand, int* __restrict__ ccnt,
                               int* __restrict__ rowbad) {
    const int tid = threadIdx.x, lane = tid & 63, wv = tid >> 6;
    const int w = blockIdx.x * 4 + wv;            // 0..1023
#pragma unroll
    for (int q = 0; q < 4; q++) {
        const int a = w * 4 + q;                  // 0..4095
        u32 n = acnt[a];
        if ((u32)lane < n) {
            u64 ent = arena[(size_t)a * ACAP + lane];
            u32 e = (u32)ent;
            u32 row = (u32)(((u64)e * 5629499535ull) >> 49);   // exact /100000
            u32 item = e - row * 100000u;
            int slot = atomicAdd(&ccnt[row], 1);
            if (slot < CCAP) cand[(size_t)row * CCAP + slot] =
                                 (ent & 0xFFFFFFFF00000000ull) | (u64)item;
            else rowbad[row] = 1;
        }
    }
}

// ---------------- K4: merge: exact candidate dots + certify ---------------
// Candidates carry exact f32 scores (R5-verified op order == reference) =>
// cert is t1 > smb + E1 + 6.001 (every non-candidate has g <= 6.0).
__global__ void merge_kernel(const u32* __restrict__ wsBm, const float* __restrict__ wsAM4,
                             const float* __restrict__ unorm, const u64* __restrict__ cand,
                             const int* __restrict__ ccnt, const int* __restrict__ rowbad,
                             const float* __restrict__ uif, const float* __restrict__ A,
                             const int* __restrict__ need_replace,
                             u64* __restrict__ packed, int* __restrict__ rowlist,
                             int* __restrict__ cnt, float* __restrict__ out) {
    const int row = blockIdx.x, t = threadIdx.x;     // 64 threads = 1 wave
    __shared__ float Us[64];
    Us[t] = uif[row * 64 + t];
    __syncthreads();

    float am = 0.f;
    for (int i = t; i < AM4_N; i += 64) am = fmaxf(am, wsAM4[i]);
    const float smb = unpack_om(wsBm[row]);

    const int ncand = ccnt[row];
    const bool bad = (rowbad[row] != 0) || (ncand > CCAP);
    const int n = ncand < CCAP ? ncand : CCAP;

    u64 pk = 0ull;
    for (int j = t; j < n; j += 64) {
        u64 ent = cand[(size_t)row * CCAP + j];
        u32 item = (u32)ent;
        float g = gumbel_from_bits((u32)(ent >> 32));
        const float4* a4 = (const float4*)(A + (size_t)item * DDIM);
        float s0 = 0.f, s1 = 0.f;
#pragma unroll
        for (int k = 0; k < 16; k += 2) {     // R5-verified op order (exact)
            float4 x = a4[k];
            float4 y = a4[k + 1];
            s0 = fmaf(x.x, Us[4*k    ], s0);
            s0 = fmaf(x.y, Us[4*k + 1], s0);
            s0 = fmaf(x.z, Us[4*k + 2], s0);
            s0 = fmaf(x.w, Us[4*k + 3], s0);
            s1 = fmaf(y.x, Us[4*k + 4], s1);
            s1 = fmaf(y.y, Us[4*k + 5], s1);
            s1 = fmaf(y.z, Us[4*k + 6], s1);
            s1 = fmaf(y.w, Us[4*k + 7], s1);
        }
        float v = (s0 + s1) + g;
        u64 c = ((u64)order_map(v) << 32) | (u32)(~item);
        pk = (c > pk) ? c : pk;
    }
#pragma unroll
    for (int off = 1; off < 64; off <<= 1) {
        u64 o = __shfl_xor(pk, off);
        pk = (o > pk) ? o : pk;
        am = fmaxf(am, __shfl_xor(am, off));
    }
    // 1-term bf16 margin: |s_f32 - s_bf16| <= ~0.004*|a||u|; 2x headroom
    const float E1 = 8.0e-3f * unorm[row] * am + 1.0e-4f;
    const float v1 = unpack_val(pk);        // NaN when pk==0 -> cert false
    if (!bad && (v1 > smb + E1 + G_TE)) {
        const int idx = (int)(~(u32)(pk & 0xFFFFFFFFull));
        float fr = A[(size_t)idx * DDIM + t];
        out[OUT_FEAT + row * DDIM + t] = fr;
        int   item = need_replace[2 * row + 1];
        float fa   = A[(size_t)item * DDIM + t];
        float dot = fa * fr, na2 = fa * fa, nb2 = fr * fr;
#pragma unroll
        for (int o = 32; o >= 1; o >>= 1) {
            dot += __shfl_down(dot, o);
            na2 += __shfl_down(na2, o);
            nb2 += __shfl_down(nb2, o);
        }
        if (t == 0) {
            out[row] = (float)idx;
            float denom = fmaxf(sqrtf(na2) * sqrtf(nb2), 1e-6f);
            float sim = (dot / denom + 1.0f) * 0.5f;
            float d = sim - 0.5f;
            atomicAdd(&out[OUT_LOSS], d * d * (1.0f / 512.0f));
            atomicAdd(&out[OUT_MSIM], sim * (1.0f / 512.0f));
        }
    } else if (t == 0) {
        packed[row] = 0ull;
        rowlist[atomicAdd(cnt, 1)] = row;
    }
}

// ---------------- K5: exact f32 fallback (512 blocks); last block resolves -
__global__ void fallback_kernel(const float* __restrict__ A, const float* __restrict__ uif,
                                const int* __restrict__ rowlist, const int* __restrict__ cnt,
                                const int* __restrict__ need_replace,
                                u64* __restrict__ packed, int* __restrict__ done,
                                float* __restrict__ out) {
    __shared__ float Us[64];
    __shared__ int   sh_last;
    const int t  = threadIdx.x;          // 0..255
    const int xb = blockIdx.x;           // 0..63
    const int total = *cnt;
    const int iend = min((xb + 1) * FB_CHUNK, NITEMS);

    for (int li = blockIdx.y; li < total; li += FB_Y) {
        const int row = rowlist[li];
        __syncthreads();
        if (t < 64) Us[t] = uif[row * 64 + t];
        __syncthreads();
        u64 pk = 0ull;
        for (int item = xb * FB_CHUNK + t; item < iend; item += 256) {
            u32 rb  = threefry_0_42_xor((u32)row * (u32)NITEMS + (u32)item);
            float g = gumbel_from_bits(rb);
            const float4* a4 = (const float4*)(A + (size_t)item * DDIM);
            float s0 = 0.f, s1 = 0.f;
#pragma unroll
            for (int k = 0; k < 16; k += 2) {     // R5-verified op order
                float4 x = a4[k];
                float4 y = a4[k + 1];
                s0 = fmaf(x.x, Us[4*k    ], s0);
                s0 = fmaf(x.y, Us[4*k + 1], s0);
                s0 = fmaf(x.z, Us[4*k + 2], s0);
                s0 = fmaf(x.w, Us[4*k + 3], s0);
                s1 = fmaf(y.x, Us[4*k + 4], s1);
                s1 = fmaf(y.y, Us[4*k + 5], s1);
                s1 = fmaf(y.z, Us[4*k + 6], s1);
                s1 = fmaf(y.w, Us[4*k + 7], s1);
            }
            float v = (s0 + s1) + g;
            u64 c = ((u64)order_map(v) << 32) | (u32)(~(u32)item);
            pk = (c > pk) ? c : pk;
        }
#pragma unroll
        for (int off = 1; off < 64; off <<= 1) {
            u64 o = __shfl_xor(pk, off);
            pk = (o > pk) ? o : pk;
        }
        if ((t & 63) == 0) atomicMax(&packed[row], pk);
        __syncthreads();
        if (t == 0) {
            __threadfence();
            sh_last = (atomicAdd(&done[li], 1) == FB_X - 1) ? 1 : 0;
        }
        __syncthreads();
        if (sh_last && t < 64) {               // last contributor resolves row
            u64 fin = atomicMax(&packed[row], 0ull);   // coherent read
            const int idx = (int)(~(u32)(fin & 0xFFFFFFFFull));
            float fr = A[(size_t)idx * DDIM + t];
            out[OUT_FEAT + row * DDIM + t] = fr;
            int   item = need_replace[2 * row + 1];
            float fa   = A[(size_t)item * DDIM + t];
            float dot = fa * fr, na2 = fa * fa, nb2 = fr * fr;
#pragma unroll
            for (int o = 32; o >= 1; o >>= 1) {
                dot += __shfl_down(dot, o);
                na2 += __shfl_down(na2, o);
                nb2 += __shfl_down(nb2, o);
            }
            if (t == 0) {
                out[row] = (float)idx;
                float denom = fmaxf(sqrtf(na2) * sqrtf(nb2), 1e-6f);
                float sim = (dot / denom + 1.0f) * 0.5f;
                float d = sim - 0.5f;
                atomicAdd(&out[OUT_LOSS], d * d * (1.0f / 512.0f));
                atomicAdd(&out[OUT_MSIM], sim * (1.0f / 512.0f));
            }
        }
        __syncthreads();
    }
}

extern "C" void kernel_launch(void* const* d_in, const int* in_sizes, int n_in,
                              void* d_out, int out_size, void* d_ws, size_t ws_size,
                              hipStream_t stream) {
    (void)in_sizes; (void)n_in; (void)out_size; (void)ws_size;
    const int*   need_replace = (const int*)d_in[0];
    const float* UF           = (const float*)d_in[1];
    const float* A            = (const float*)d_in[2];
    const float* W            = (const float*)d_in[3];
    const float* bias         = (const float*)d_in[4];
    float* out = (float*)d_out;

    char* ws = (char*)d_ws;                              // ~3.84 MB total
    u64*   arena   = (u64*)  (ws);                       // 4096*64*8 = 2097152
    u64*   cand    = (u64*)  (ws + 2097152);             // 512*384*8 = 1572864
    float* uif     = (float*)(ws + 3670016);             // 131072
    u64*   packed  = (u64*)  (ws + 3801088);             // 4096
    u32*   acnt    = (u32*)  (ws + 3805184);             // 16384
    float* unorm   = (float*)(ws + 3821568);             // 2048
    float* wsAM4   = (float*)(ws + 3823616);             // 6256
    int*   ccnt    = (int*)  (ws + 3829872);             // 2048
    int*   rowbad  = (int*)  (ws + 3831920);             // 2048
    int*   rowlist = (int*)  (ws + 3833968);             // 2048
    int*   cnt     = (int*)  (ws + 3836016);             // 4
    int*   done    = (int*)  (ws + 3836020);             // 2048
    u32*   wsBm    = (u32*)  (ws + 3838068);             // 2048

    prep_kernel<<<519, 256, 0, stream>>>(UF, W, bias, A, uif, unorm, wsAM4, cnt, done,
                                         ccnt, rowbad, wsBm, out);
    phase1f_kernel<<<2048, 256, 0, stream>>>(A, uif, wsBm, arena, acnt, rowbad);
    compact_kernel<<<256, 256, 0, stream>>>(arena, acnt, cand, ccnt, rowbad);
    merge_kernel<<<BROWS, 64, 0, stream>>>(wsBm, wsAM4, unorm, cand, ccnt, rowbad,
                                           uif, A, need_replace, packed, rowlist, cnt, out);
    fallback_kernel<<<dim3(FB_X, FB_Y), 256, 0, stream>>>(A, uif, rowlist, cnt,
                                                          need_replace, packed, done, out);
}

// Round 10
// 373.379 us; speedup vs baseline: 6.1161x; 1.1627x over previous
//
#include <hip/hip_runtime.h>
#include <cstdint>

#define NITEMS   100000
#define BROWS    512
#define DDIM     64
#define S_BLOCKS 391        // prep norm-blocks (256 items each) -> wsAM4
#define AM4_N    (S_BLOCKS * 4)
#define NTILES   3125       // 100000 / 32, exact
#define NBLK     2048       // phase1f grid: uniform blocks, 8/CU exactly
#define MF_X     512        // MFMA sub-phase: xb 0..511, tile stride 512
#define TF_L     100        // items per TF thread; 512000 thr * 100 = 51.2M exact
#define TF_THR   512000     // threads participating in TF phase
#define WCAP     64         // per-wave LDS event arena (mean 15.9, +12 sigma)
#define CCAP     384        // per-row candidate list (mean 247.6, +8.7 sigma)
#define FB_X     64         // fallback item-chunks (1568 items each)
#define FB_Y     8
#define FB_CHUNK 1568
#define OUT_FEAT 512
#define OUT_LOSS (512 + 512 * 64)
#define OUT_MSIM (OUT_LOSS + 1)

// Gumbel filter: g monotone in bits; bits >= T <=> g may exceed 6.0.
#define BITS_RAW_T 4284334592u
#define G_TE       6.001f

typedef __attribute__((ext_vector_type(8)))  short  bf16x8;
typedef __attribute__((ext_vector_type(16))) float  f32x16;
typedef unsigned long long u64;
typedef uint32_t u32;

#define ROTL(x, r) __builtin_amdgcn_alignbit((x), (x), 32u - (r))

// ---------------- Threefry-2x32-20, key=(0,42). VERIFIED R4 (absmax 0.0):
// partitionable scheme, counters (hi=0, lo=e), output = bits1 ^ bits2.
__device__ __forceinline__ u32 threefry_0_42_xor(u32 e) {
    const u32 K1 = 42u;
    const u32 K2 = 0x1BD11BDAu ^ 42u;   // K0 = 0
    u32 x0 = 0u;
    u32 x1 = e + K1;
#define TFR(r) { x0 += x1; x1 = ROTL(x1, r) ^ x0; }
    TFR(13u) TFR(15u) TFR(26u) TFR(6u)
    x0 += K1;  x1 += K2 + 1u;
    TFR(17u) TFR(29u) TFR(16u) TFR(24u)
    x0 += K2;  x1 += 2u;
    TFR(13u) TFR(15u) TFR(26u) TFR(6u)
    x1 += K1 + 3u;
    TFR(17u) TFR(29u) TFR(16u) TFR(24u)
    x0 += K1;  x1 += K2 + 4u;
    TFR(13u) TFR(15u) TFR(26u) TFR(6u)
    x0 += K2;  x1 += 5u;
#undef TFR
    return x0 ^ x1;
}

// Four independent chains interleaved: ILP 4 on the serial threefry chain.
// Bit-identical to threefry_0_42_xor per chain by construction.
__device__ __forceinline__ void threefry_quad(u32 e0, u32 e1, u32 e2, u32 e3,
                                              u32& r0, u32& r1, u32& r2, u32& r3) {
    const u32 K1 = 42u;
    const u32 K2 = 0x1BD11BDAu ^ 42u;
    u32 a0 = 0u, a1 = e0 + K1;
    u32 b0 = 0u, b1 = e1 + K1;
    u32 c0 = 0u, c1 = e2 + K1;
    u32 d0 = 0u, d1 = e3 + K1;
#define TFR4(r) { a0 += a1; b0 += b1; c0 += c1; d0 += d1; \
                  a1 = ROTL(a1, r) ^ a0; b1 = ROTL(b1, r) ^ b0; \
                  c1 = ROTL(c1, r) ^ c0; d1 = ROTL(d1, r) ^ d0; }
    TFR4(13u) TFR4(15u) TFR4(26u) TFR4(6u)
    a0 += K1; a1 += K2 + 1u;  b0 += K1; b1 += K2 + 1u;
    c0 += K1; c1 += K2 + 1u;  d0 += K1; d1 += K2 + 1u;
    TFR4(17u) TFR4(29u) TFR4(16u) TFR4(24u)
    a0 += K2; a1 += 2u;       b0 += K2; b1 += 2u;
    c0 += K2; c1 += 2u;       d0 += K2; d1 += 2u;
    TFR4(13u) TFR4(15u) TFR4(26u) TFR4(6u)
    a1 += K1 + 3u;            b1 += K1 + 3u;
    c1 += K1 + 3u;            d1 += K1 + 3u;
    TFR4(17u) TFR4(29u) TFR4(16u) TFR4(24u)
    a0 += K1; a1 += K2 + 4u;  b0 += K1; b1 += K2 + 4u;
    c0 += K1; c1 += K2 + 4u;  d0 += K1; d1 += K2 + 4u;
    TFR4(13u) TFR4(15u) TFR4(26u) TFR4(6u)
    a0 += K2; a1 += 5u;       b0 += K2; b1 += 5u;
    c0 += K2; c1 += 5u;       d0 += K2; d1 += 5u;
#undef TFR4
    r0 = a0 ^ a1; r1 = b0 ^ b1; r2 = c0 ^ c1; r3 = d0 ^ d1;
}

__device__ __forceinline__ float gumbel_from_bits(u32 b) {   // precise logf REQUIRED
    float f = __uint_as_float((b >> 9) | 0x3F800000u) - 1.0f;
    f = fmaxf(f, 1.17549435e-38f);
    return -logf(-logf(f));
}
__device__ __forceinline__ u32 order_map(float v) {
    u32 x = __float_as_uint(v);
    return (x & 0x80000000u) ? ~x : (x | 0x80000000u);
}
__device__ __forceinline__ float unpack_val(u64 p) {
    u32 x = (u32)(p >> 32);
    u32 f = (x & 0x80000000u) ? (x & 0x7FFFFFFFu) : ~x;
    return __uint_as_float(f);
}
__device__ __forceinline__ float unpack_om(u32 x) {
    u32 f = (x & 0x80000000u) ? (x & 0x7FFFFFFFu) : ~x;
    return __uint_as_float(f);
}
__device__ __forceinline__ short f32_to_bf16_rne(float f) {
    u32 b = __float_as_uint(f);
    u32 r = (b + 0x7FFFu + ((b >> 16) & 1u)) >> 16;
    return (short)r;
}

// ---------------- K1: prep = uif GEMM (W^T in LDS) + norms + zero state ----
__global__ void prep_kernel(const float* __restrict__ UF, const float* __restrict__ W,
                            const float* __restrict__ bias, const float* __restrict__ A,
                            float* __restrict__ uif, float* __restrict__ unorm,
                            float* __restrict__ wsAM4, int* __restrict__ cnt,
                            int* __restrict__ done, int* __restrict__ ccnt,
                            int* __restrict__ rowbad, u32* __restrict__ wsBm,
                            float* __restrict__ out) {
    const int t = threadIdx.x, b = blockIdx.x;
    if (b == 0) {
        if (t == 0) { *cnt = 0; out[OUT_LOSS] = 0.f; out[OUT_MSIM] = 0.f; }
        done[t] = 0;   done[t + 256] = 0;
        ccnt[t] = 0;   ccnt[t + 256] = 0;
        rowbad[t] = 0; rowbad[t + 256] = 0;
        wsBm[t] = 0u;  wsBm[t + 256] = 0u;
    }
    if (b < 128) {
        __shared__ float Wt[128 * 65];
        for (int i = t; i < 8192; i += 256) {
            int d = i >> 7, k = i & 127;
            Wt[k * 65 + d] = W[i];
        }
        __syncthreads();
        const int row = b * 4 + (t >> 6);
        const int d   = t & 63;
        const float* u = UF + row * 128;
        float s = 0.f;
#pragma unroll 4
        for (int k = 0; k < 128; k++) s = fmaf(u[k], Wt[k * 65 + d], s);
        s += bias[d];
        uif[row * 64 + d] = s;
        float q = s * s;
#pragma unroll
        for (int o = 32; o >= 1; o >>= 1) q += __shfl_xor(q, o);
        if (d == 0) unorm[row] = sqrtf(q);
    } else {
        const int item = (b - 128) * 256 + t;
        float q = 0.f;
        if (item < NITEMS) {
            const float4* r = (const float4*)(A + (size_t)item * DDIM);
#pragma unroll
            for (int k = 0; k < 16; k++) {
                float4 x = r[k];
                q = fmaf(x.x, x.x, q); q = fmaf(x.y, x.y, q);
                q = fmaf(x.z, x.z, q); q = fmaf(x.w, x.w, q);
            }
        }
        float n = sqrtf(q);
#pragma unroll
        for (int o = 32; o >= 1; o >>= 1) n = fmaxf(n, __shfl_xor(n, o));
        if ((t & 63) == 0) wsAM4[(b - 128) * 4 + (t >> 6)] = n;
    }
}

// ---------------- K2: UNIFORM blocks: phase A (MFMA row-max) then phase B
// (TF filter + inline per-wave compaction). Every block identical => load
// balance immune to the (undefined) block->CU/XCD dispatch mapping, which
// broke R3 (XCD segregation) and R5 (CU segregation). grid 2048 @
// launch_bounds(256,8) = exactly 8 blocks/CU, single residency round.
__global__ __launch_bounds__(256, 8) void phase1f_kernel(
        const float* __restrict__ A, const float* __restrict__ uif,
        u32* __restrict__ wsBm, u64* __restrict__ cand,
        int* __restrict__ ccnt, int* __restrict__ rowbad) {
    __shared__ bf16x8 sh_ah[4 * 64];
    __shared__ u32 qbits[4][WCAP];
    __shared__ u32 qe[4][WCAP];
    const int bid  = blockIdx.x;
    const int tid  = threadIdx.x;
    const int lane = tid & 63;
    const int wv   = tid >> 6;

    // ================= Phase A: MFMA row-max (single-term bf16) ============
    {
        const int xb = bid & (MF_X - 1);           // 0..511
        const int rg = bid >> 9;                   // 0..3 (same-xb pair: +512 = same XCD)
        const int row   = rg * 128 + wv * 32 + (lane & 31);
        const int khalf = (lane >> 5) * 8;

        bf16x8 uh[4];
#pragma unroll
        for (int s = 0; s < 4; s++) {
            const float* src = uif + row * 64 + khalf + 16 * s;
            float4 v0 = *(const float4*)src;
            float4 v1 = *(const float4*)(src + 4);
            float vv[8] = {v0.x, v0.y, v0.z, v0.w, v1.x, v1.y, v1.z, v1.w};
            bf16x8 h;
#pragma unroll
            for (int j = 0; j < 8; j++) h[j] = f32_to_bf16_rne(vv[j]);
            uh[s] = h;
        }

        float sm = -3.0e38f;
        const int s_i   = tid & 31;
        const int s_c   = tid >> 5;
        const int s_dst = (s_c >> 1) * 64 + s_i + 32 * (s_c & 1);   // R7-verified map
        const float* s_srcbase = A + (size_t)s_i * 64 + 8 * s_c;

        int t_idx = xb;                             // < 512 < NTILES always
        float4 p0 = *(const float4*)(s_srcbase + (size_t)t_idx * 2048);
        float4 p1 = *(const float4*)(s_srcbase + (size_t)t_idx * 2048 + 4);

        while (t_idx < NTILES) {
            bf16x8 h;
            {
                float vv[8] = {p0.x, p0.y, p0.z, p0.w, p1.x, p1.y, p1.z, p1.w};
#pragma unroll
                for (int j = 0; j < 8; j++) h[j] = f32_to_bf16_rne(vv[j]);
            }
            __syncthreads();
            sh_ah[s_dst] = h;
            __syncthreads();
            t_idx += MF_X;
            if (t_idx < NTILES) {
                const float* src = s_srcbase + (size_t)t_idx * 2048;
                p0 = *(const float4*)src;
                p1 = *(const float4*)(src + 4);
            }

            f32x16 acc;
#pragma unroll
            for (int z = 0; z < 16; z++) acc[z] = 0.0f;
#pragma unroll
            for (int s = 0; s < 4; s++)
                acc = __builtin_amdgcn_mfma_f32_32x32x16_bf16(sh_ah[s * 64 + lane],
                                                              uh[s], acc, 0, 0, 0);
#pragma unroll
            for (int i = 0; i < 16; i++) sm = fmaxf(sm, acc[i]);
        }

        sm = fmaxf(sm, __shfl_xor(sm, 32));
        if (lane < 32) atomicMax(&wsBm[row], order_map(sm));   // fire-and-forget
    }

    // ================= Phase B: threefry filter (lean VALU loop) ===========
    const int gid = bid * 256 + tid;
    u32 cq = 0;
    if (gid < TF_THR) {                    // block-uniform predicate (TF_THR%256==0)
        u32 e = (u32)gid * (u32)TF_L;      // thread covers [e, e+100) exactly in-range
        const u64 lanelt = (lane == 0) ? 0ull : (~0ull >> (64 - lane));
#pragma unroll 1
        for (int k = 0; k < TF_L / 4; k++) {
            u32 r0, r1, r2, r3;
            threefry_quad(e, e + 1u, e + 2u, e + 3u, r0, r1, r2, r3);
            bool v0 = r0 >= BITS_RAW_T, v1 = r1 >= BITS_RAW_T;
            bool v2 = r2 >= BITS_RAW_T, v3 = r3 >= BITS_RAW_T;
            u64 m0 = __ballot(v0), m1 = __ballot(v1);
            u64 m2 = __ballot(v2), m3 = __ballot(v3);
            if (v0) { u32 ix = cq + (u32)__popcll(m0 & lanelt);
                      if (ix < WCAP) { qbits[wv][ix] = r0; qe[wv][ix] = e; } }
            cq += (u32)__popcll(m0);
            if (v1) { u32 ix = cq + (u32)__popcll(m1 & lanelt);
                      if (ix < WCAP) { qbits[wv][ix] = r1; qe[wv][ix] = e + 1u; } }
            cq += (u32)__popcll(m1);
            if (v2) { u32 ix = cq + (u32)__popcll(m2 & lanelt);
                      if (ix < WCAP) { qbits[wv][ix] = r2; qe[wv][ix] = e + 2u; } }
            cq += (u32)__popcll(m2);
            if (v3) { u32 ix = cq + (u32)__popcll(m3 & lanelt);
                      if (ix < WCAP) { qbits[wv][ix] = r3; qe[wv][ix] = e + 3u; } }
            cq += (u32)__popcll(m3);
            e += 4u;
        }
    }
    __syncthreads();                       // LDS arena visibility (cheap, once)

    // ---- inline compaction: each wave scatters its own arena to rows ----
    const u32 n = cq < (u32)WCAP ? cq : (u32)WCAP;
    if ((u32)lane < n) {
        u32 bits = qbits[wv][lane];
        u32 ev   = qe[wv][lane];
        u32 row  = (u32)(((u64)ev * 5629499535ull) >> 49);   // exact /100000
        u32 item = ev - row * 100000u;
        int slot = atomicAdd(&ccnt[row], 1);
        if (slot < CCAP) cand[(size_t)row * CCAP + slot] = ((u64)bits << 32) | (u64)item;
        else rowbad[row] = 1;
    }
    if (lane == 0 && cq > (u32)WCAP) {     // +12 sigma; safe path anyway
        u32 es = (u32)(bid * 256 + wv * 64) * (u32)TF_L;     // wave covers 6400 items
        u32 ee = es + (u32)(64 * TF_L) - 1u;
        rowbad[es / 100000u] = 1;
        rowbad[ee / 100000u] = 1;
    }
}

// ---------------- K3: merge: exact candidate dots + certify ---------------
// Candidates carry threefry bits; scores computed here with the R5-verified
// exact op order == reference. Cert: t1 > smb + E1 + 6.001 (non-cand g<=6).
__global__ void merge_kernel(const u32* __restrict__ wsBm, const float* __restrict__ wsAM4,
                             const float* __restrict__ unorm, const u64* __restrict__ cand,
                             const int* __restrict__ ccnt, const int* __restrict__ rowbad,
                             const float* __restrict__ uif, const float* __restrict__ A,
                             const int* __restrict__ need_replace,
                             u64* __restrict__ packed, int* __restrict__ rowlist,
                             int* __restrict__ cnt, float* __restrict__ out) {
    const int row = blockIdx.x, t = threadIdx.x;     // 64 threads = 1 wave
    __shared__ float Us[64];
    Us[t] = uif[row * 64 + t];
    __syncthreads();

    float am = 0.f;
    for (int i = t; i < AM4_N; i += 64) am = fmaxf(am, wsAM4[i]);
    const float smb = unpack_om(wsBm[row]);

    const int ncand = ccnt[row];
    const bool bad = (rowbad[row] != 0) || (ncand > CCAP);
    const int n = ncand < CCAP ? ncand : CCAP;

    u64 pk = 0ull;
    for (int j = t; j < n; j += 64) {
        u64 ent = cand[(size_t)row * CCAP + j];
        u32 item = (u32)ent;
        float g = gumbel_from_bits((u32)(ent >> 32));
        const float4* a4 = (const float4*)(A + (size_t)item * DDIM);
        float s0 = 0.f, s1 = 0.f;
#pragma unroll
        for (int k = 0; k < 16; k += 2) {     // R5-verified op order (exact)
            float4 x = a4[k];
            float4 y = a4[k + 1];
            s0 = fmaf(x.x, Us[4*k    ], s0);
            s0 = fmaf(x.y, Us[4*k + 1], s0);
            s0 = fmaf(x.z, Us[4*k + 2], s0);
            s0 = fmaf(x.w, Us[4*k + 3], s0);
            s1 = fmaf(y.x, Us[4*k + 4], s1);
            s1 = fmaf(y.y, Us[4*k + 5], s1);
            s1 = fmaf(y.z, Us[4*k + 6], s1);
            s1 = fmaf(y.w, Us[4*k + 7], s1);
        }
        float v = (s0 + s1) + g;
        u64 c = ((u64)order_map(v) << 32) | (u32)(~item);
        pk = (c > pk) ? c : pk;
    }
#pragma unroll
    for (int off = 1; off < 64; off <<= 1) {
        u64 o = __shfl_xor(pk, off);
        pk = (o > pk) ? o : pk;
        am = fmaxf(am, __shfl_xor(am, off));
    }
    // 1-term bf16 margin: |s_f32 - s_bf16| <= ~0.004*|a||u|; 2x headroom
    const float E1 = 8.0e-3f * unorm[row] * am + 1.0e-4f;
    const float v1 = unpack_val(pk);        // NaN when pk==0 -> cert false
    if (!bad && (v1 > smb + E1 + G_TE)) {
        const int idx = (int)(~(u32)(pk & 0xFFFFFFFFull));
        float fr = A[(size_t)idx * DDIM + t];
        out[OUT_FEAT + row * DDIM + t] = fr;
        int   item = need_replace[2 * row + 1];
        float fa   = A[(size_t)item * DDIM + t];
        float dot = fa * fr, na2 = fa * fa, nb2 = fr * fr;
#pragma unroll
        for (int o = 32; o >= 1; o >>= 1) {
            dot += __shfl_down(dot, o);
            na2 += __shfl_down(na2, o);
            nb2 += __shfl_down(nb2, o);
        }
        if (t == 0) {
            out[row] = (float)idx;
            float denom = fmaxf(sqrtf(na2) * sqrtf(nb2), 1e-6f);
            float sim = (dot / denom + 1.0f) * 0.5f;
            float d = sim - 0.5f;
            atomicAdd(&out[OUT_LOSS], d * d * (1.0f / 512.0f));
            atomicAdd(&out[OUT_MSIM], sim * (1.0f / 512.0f));
        }
    } else if (t == 0) {
        packed[row] = 0ull;
        rowlist[atomicAdd(cnt, 1)] = row;
    }
}

// ---------------- K4: exact f32 fallback (512 blocks); last block resolves -
__global__ void fallback_kernel(const float* __restrict__ A, const float* __restrict__ uif,
                                const int* __restrict__ rowlist, const int* __restrict__ cnt,
                                const int* __restrict__ need_replace,
                                u64* __restrict__ packed, int* __restrict__ done,
                                float* __restrict__ out) {
    __shared__ float Us[64];
    __shared__ int   sh_last;
    const int t  = threadIdx.x;          // 0..255
    const int xb = blockIdx.x;           // 0..63
    const int total = *cnt;
    const int iend = min((xb + 1) * FB_CHUNK, NITEMS);

    for (int li = blockIdx.y; li < total; li += FB_Y) {
        const int row = rowlist[li];
        __syncthreads();
        if (t < 64) Us[t] = uif[row * 64 + t];
        __syncthreads();
        u64 pk = 0ull;
        for (int item = xb * FB_CHUNK + t; item < iend; item += 256) {
            u32 rb  = threefry_0_42_xor((u32)row * (u32)NITEMS + (u32)item);
            float g = gumbel_from_bits(rb);
            const float4* a4 = (const float4*)(A + (size_t)item * DDIM);
            float s0 = 0.f, s1 = 0.f;
#pragma unroll
            for (int k = 0; k < 16; k += 2) {     // R5-verified op order
                float4 x = a4[k];
                float4 y = a4[k + 1];
                s0 = fmaf(x.x, Us[4*k    ], s0);
                s0 = fmaf(x.y, Us[4*k + 1], s0);
                s0 = fmaf(x.z, Us[4*k + 2], s0);
                s0 = fmaf(x.w, Us[4*k + 3], s0);
                s1 = fmaf(y.x, Us[4*k + 4], s1);
                s1 = fmaf(y.y, Us[4*k + 5], s1);
                s1 = fmaf(y.z, Us[4*k + 6], s1);
                s1 = fmaf(y.w, Us[4*k + 7], s1);
            }
            float v = (s0 + s1) + g;
            u64 c = ((u64)order_map(v) << 32) | (u32)(~(u32)item);
            pk = (c > pk) ? c : pk;
        }
#pragma unroll
        for (int off = 1; off < 64; off <<= 1) {
            u64 o = __shfl_xor(pk, off);
            pk = (o > pk) ? o : pk;
        }
        if ((t & 63) == 0) atomicMax(&packed[row], pk);
        __syncthreads();
        if (t == 0) {
            __threadfence();
            sh_last = (atomicAdd(&done[li], 1) == FB_X - 1) ? 1 : 0;
        }
        __syncthreads();
        if (sh_last && t < 64) {               // last contributor resolves row
            u64 fin = atomicMax(&packed[row], 0ull);   // coherent read
            const int idx = (int)(~(u32)(fin & 0xFFFFFFFFull));
            float fr = A[(size_t)idx * DDIM + t];
            out[OUT_FEAT + row * DDIM + t] = fr;
            int   item = need_replace[2 * row + 1];
            float fa   = A[(size_t)item * DDIM + t];
            float dot = fa * fr, na2 = fa * fa, nb2 = fr * fr;
#pragma unroll
            for (int o = 32; o >= 1; o >>= 1) {
                dot += __shfl_down(dot, o);
                na2 += __shfl_down(na2, o);
                nb2 += __shfl_down(nb2, o);
            }
            if (t == 0) {
                out[row] = (float)idx;
                float denom = fmaxf(sqrtf(na2) * sqrtf(nb2), 1e-6f);
                float sim = (dot / denom + 1.0f) * 0.5f;
                float d = sim - 0.5f;
                atomicAdd(&out[OUT_LOSS], d * d * (1.0f / 512.0f));
                atomicAdd(&out[OUT_MSIM], sim * (1.0f / 512.0f));
            }
        }
        __syncthreads();
    }
}

extern "C" void kernel_launch(void* const* d_in, const int* in_sizes, int n_in,
                              void* d_out, int out_size, void* d_ws, size_t ws_size,
                              hipStream_t stream) {
    (void)in_sizes; (void)n_in; (void)out_size; (void)ws_size;
    const int*   need_replace = (const int*)d_in[0];
    const float* UF           = (const float*)d_in[1];
    const float* A            = (const float*)d_in[2];
    const float* W            = (const float*)d_in[3];
    const float* bias         = (const float*)d_in[4];
    float* out = (float*)d_out;

    char* ws = (char*)d_ws;                              // ~1.73 MB total
    u64*   cand    = (u64*)  (ws);                       // 512*384*8 = 1572864
    float* uif     = (float*)(ws + 1572864);             // 131072
    u64*   packed  = (u64*)  (ws + 1703936);             // 4096
    float* unorm   = (float*)(ws + 1708032);             // 2048
    float* wsAM4   = (float*)(ws + 1710080);             // 6256
    int*   ccnt    = (int*)  (ws + 1716336);             // 2048
    int*   rowbad  = (int*)  (ws + 1718384);             // 2048
    int*   rowlist = (int*)  (ws + 1720432);             // 2048
    int*   cnt     = (int*)  (ws + 1722480);             // 4
    int*   done    = (int*)  (ws + 1722484);             // 2048
    u32*   wsBm    = (u32*)  (ws + 1724532);             // 2048

    prep_kernel<<<519, 256, 0, stream>>>(UF, W, bias, A, uif, unorm, wsAM4, cnt, done,
                                         ccnt, rowbad, wsBm, out);
    phase1f_kernel<<<NBLK, 256, 0, stream>>>(A, uif, wsBm, cand, ccnt, rowbad);
    merge_kernel<<<BROWS, 64, 0, stream>>>(wsBm, wsAM4, unorm, cand, ccnt, rowbad,
                                           uif, A, need_replace, packed, rowlist, cnt, out);
    fallback_kernel<<<dim3(FB_X, FB_Y), 256, 0, stream>>>(A, uif, rowlist, cnt,
                                                          need_replace, packed, done, out);
}

// Round 13
// 249.596 us; speedup vs baseline: 9.1492x; 1.4959x over previous
//
#include <hip/hip_runtime.h>
#include <cstdint>

#define NITEMS   100000
#define BROWS    512
#define DDIM     64
#define S_BLOCKS 391        // prep norm-blocks (256 items each) -> wsAM4
#define AM4_N    (S_BLOCKS * 4)
#define SB_OUT   256        // phase1 grid.x; tile stride (R1-proven geometry)
#define NTILES   3125       // 100000 / 32, exact
#define CCAP     384        // per-row candidate list (mean 247.6, +8.7 sigma)
#define FB_X     64         // fallback item-chunks (1568 items each)
#define FB_Y     8
#define FB_CHUNK 1568
#define OUT_FEAT 512
#define OUT_LOSS (512 + 512 * 64)
#define OUT_MSIM (OUT_LOSS + 1)

// Gumbel filter: g monotone in bits; bits >= T <=> g may exceed 6.0.
#define BITS_RAW_T 4284334592u
#define G_TE       6.001f

typedef __attribute__((ext_vector_type(8)))  short  bf16x8;
typedef __attribute__((ext_vector_type(16))) float  f32x16;
typedef unsigned long long u64;
typedef uint32_t u32;

#define ROTL(x, r) __builtin_amdgcn_alignbit((x), (x), 32u - (r))

// ---------------- Threefry-2x32-20, key=(0,42). VERIFIED (absmax 0.0):
// partitionable scheme, counters (hi=0, lo=e), output = bits1 ^ bits2.
__device__ __forceinline__ u32 threefry_0_42_xor(u32 e) {
    const u32 K1 = 42u;
    const u32 K2 = 0x1BD11BDAu ^ 42u;   // K0 = 0
    u32 x0 = 0u;
    u32 x1 = e + K1;
#define TFR(r) { x0 += x1; x1 = ROTL(x1, r) ^ x0; }
    TFR(13u) TFR(15u) TFR(26u) TFR(6u)
    x0 += K1;  x1 += K2 + 1u;
    TFR(17u) TFR(29u) TFR(16u) TFR(24u)
    x0 += K2;  x1 += 2u;
    TFR(13u) TFR(15u) TFR(26u) TFR(6u)
    x1 += K1 + 3u;
    TFR(17u) TFR(29u) TFR(16u) TFR(24u)
    x0 += K1;  x1 += K2 + 4u;
    TFR(13u) TFR(15u) TFR(26u) TFR(6u)
    x0 += K2;  x1 += 5u;
#undef TFR
    return x0 ^ x1;
}

// Four independent chains interleaved: ILP 4 on the serial threefry chain.
// Bit-identical to threefry_0_42_xor per chain by construction.
__device__ __forceinline__ void threefry_quad(u32 e0, u32 e1, u32 e2, u32 e3,
                                              u32& r0, u32& r1, u32& r2, u32& r3) {
    const u32 K1 = 42u;
    const u32 K2 = 0x1BD11BDAu ^ 42u;
    u32 a0 = 0u, a1 = e0 + K1;
    u32 b0 = 0u, b1 = e1 + K1;
    u32 c0 = 0u, c1 = e2 + K1;
    u32 d0 = 0u, d1 = e3 + K1;
#define TFR4(r) { a0 += a1; b0 += b1; c0 += c1; d0 += d1; \
                  a1 = ROTL(a1, r) ^ a0; b1 = ROTL(b1, r) ^ b0; \
                  c1 = ROTL(c1, r) ^ c0; d1 = ROTL(d1, r) ^ d0; }
    TFR4(13u) TFR4(15u) TFR4(26u) TFR4(6u)
    a0 += K1; a1 += K2 + 1u;  b0 += K1; b1 += K2 + 1u;
    c0 += K1; c1 += K2 + 1u;  d0 += K1; d1 += K2 + 1u;
    TFR4(17u) TFR4(29u) TFR4(16u) TFR4(24u)
    a0 += K2; a1 += 2u;       b0 += K2; b1 += 2u;
    c0 += K2; c1 += 2u;       d0 += K2; d1 += 2u;
    TFR4(13u) TFR4(15u) TFR4(26u) TFR4(6u)
    a1 += K1 + 3u;            b1 += K1 + 3u;
    c1 += K1 + 3u;            d1 += K1 + 3u;
    TFR4(17u) TFR4(29u) TFR4(16u) TFR4(24u)
    a0 += K1; a1 += K2 + 4u;  b0 += K1; b1 += K2 + 4u;
    c0 += K1; c1 += K2 + 4u;  d0 += K1; d1 += K2 + 4u;
    TFR4(13u) TFR4(15u) TFR4(26u) TFR4(6u)
    a0 += K2; a1 += 5u;       b0 += K2; b1 += 5u;
    c0 += K2; c1 += 5u;       d0 += K2; d1 += 5u;
#undef TFR4
    r0 = a0 ^ a1; r1 = b0 ^ b1; r2 = c0 ^ c1; r3 = d0 ^ d1;
}

__device__ __forceinline__ float gumbel_from_bits(u32 b) {   // precise logf REQUIRED
    float f = __uint_as_float((b >> 9) | 0x3F800000u) - 1.0f;
    f = fmaxf(f, 1.17549435e-38f);
    return -logf(-logf(f));
}
__device__ __forceinline__ u32 order_map(float v) {
    u32 x = __float_as_uint(v);
    return (x & 0x80000000u) ? ~x : (x | 0x80000000u);
}
__device__ __forceinline__ float unpack_val(u64 p) {
    u32 x = (u32)(p >> 32);
    u32 f = (x & 0x80000000u) ? (x & 0x7FFFFFFFu) : ~x;
    return __uint_as_float(f);
}
__device__ __forceinline__ float unpack_om(u32 x) {
    u32 f = (x & 0x80000000u) ? (x & 0x7FFFFFFFu) : ~x;
    return __uint_as_float(f);
}
__device__ __forceinline__ short f32_to_bf16_rne(float f) {
    u32 b = __float_as_uint(f);
    u32 r = (b + 0x7FFFu + ((b >> 16) & 1u)) >> 16;
    return (short)r;
}

// ---------------- K1: prep = uif GEMM (W^T in LDS) + norms + zero state ----
__global__ void prep_kernel(const float* __restrict__ UF, const float* __restrict__ W,
                            const float* __restrict__ bias, const float* __restrict__ A,
                            float* __restrict__ uif, float* __restrict__ unorm,
                            float* __restrict__ wsAM4, int* __restrict__ cnt,
                            int* __restrict__ done, int* __restrict__ ccnt,
                            int* __restrict__ rowbad, u32* __restrict__ wsBm,
                            float* __restrict__ out) {
    const int t = threadIdx.x, b = blockIdx.x;
    if (b == 0) {
        if (t == 0) { *cnt = 0; out[OUT_LOSS] = 0.f; out[OUT_MSIM] = 0.f; }
        done[t] = 0;   done[t + 256] = 0;
        ccnt[t] = 0;   ccnt[t + 256] = 0;
        rowbad[t] = 0; rowbad[t + 256] = 0;
        wsBm[t] = 0u;  wsBm[t + 256] = 0u;
    }
    if (b < 128) {
        __shared__ float Wt[128 * 65];
        for (int i = t; i < 8192; i += 256) {
            int d = i >> 7, k = i & 127;
            Wt[k * 65 + d] = W[i];
        }
        __syncthreads();
        const int row = b * 4 + (t >> 6);
        const int d   = t & 63;
        const float* u = UF + row * 128;
        float s = 0.f;
#pragma unroll 4
        for (int k = 0; k < 128; k++) s = fmaf(u[k], Wt[k * 65 + d], s);
        s += bias[d];
        uif[row * 64 + d] = s;
        float q = s * s;
#pragma unroll
        for (int o = 32; o >= 1; o >>= 1) q += __shfl_xor(q, o);
        if (d == 0) unorm[row] = sqrtf(q);
    } else {
        const int item = (b - 128) * 256 + t;
        float q = 0.f;
        if (item < NITEMS) {
            const float4* r = (const float4*)(A + (size_t)item * DDIM);
#pragma unroll
            for (int k = 0; k < 16; k++) {
                float4 x = r[k];
                q = fmaf(x.x, x.x, q); q = fmaf(x.y, x.y, q);
                q = fmaf(x.z, x.z, q); q = fmaf(x.w, x.w, q);
            }
        }
        float n = sqrtf(q);
#pragma unroll
        for (int o = 32; o >= 1; o >>= 1) n = fmaxf(n, __shfl_xor(n, o));
        if ((t & 63) == 0) wsAM4[(b - 128) * 4 + (t >> 6)] = n;
    }
}

// ---------------- K2: phase1 = R1's PROVEN structure (139.8us), minus work:
// single-term bf16 MFMA (4/tile not 12), no inline gumbel/top-2/bound.
// Outputs: per-row bf16 score max (wsBm atomicMax) + rare candidate pushes
// (bits,item) to per-row lists. Cert/exact-score moved to merge (validated
// R10: absmax 0.0 with E1 margin + exact rescoring).
__global__ __launch_bounds__(256, 6) void phase1_kernel(
        const float* __restrict__ A, const float* __restrict__ uif,
        u32* __restrict__ wsBm, u64* __restrict__ cand,
        int* __restrict__ ccnt, int* __restrict__ rowbad) {
    __shared__ bf16x8 sh_ah[4 * 64];
    const int tid  = threadIdx.x;
    const int lane = tid & 63;
    const int wv   = tid >> 6;
    const int rg   = blockIdx.y;
    const int xb   = blockIdx.x;                 // 0..255
    const int row   = rg * 128 + wv * 32 + (lane & 31);
    const int khalf = (lane >> 5) * 8;

    bf16x8 uh[4];
#pragma unroll
    for (int s = 0; s < 4; s++) {
        const float* src = uif + row * 64 + khalf + 16 * s;
        float4 v0 = *(const float4*)src;
        float4 v1 = *(const float4*)(src + 4);
        float vv[8] = {v0.x, v0.y, v0.z, v0.w, v1.x, v1.y, v1.z, v1.w};
        bf16x8 h;
#pragma unroll
        for (int j = 0; j < 8; j++) h[j] = f32_to_bf16_rne(vv[j]);
        uh[s] = h;
    }

    float sm = -3.0e38f;
    const u32 rowbase_e = (u32)row * (u32)NITEMS;

    const int s_i   = tid & 31;
    const int s_c   = tid >> 5;
    const int s_dst = (s_c >> 1) * 64 + s_i + 32 * (s_c & 1);   // R7-verified map
    const float* s_srcbase = A + (size_t)s_i * 64 + 8 * s_c;

    int t_idx = xb;
    float4 p0 = *(const float4*)(s_srcbase + (size_t)t_idx * 2048);
    float4 p1 = *(const float4*)(s_srcbase + (size_t)t_idx * 2048 + 4);

    while (t_idx < NTILES) {
        const int tb = t_idx * 32;
        bf16x8 h;
        {
            float vv[8] = {p0.x, p0.y, p0.z, p0.w, p1.x, p1.y, p1.z, p1.w};
#pragma unroll
            for (int j = 0; j < 8; j++) h[j] = f32_to_bf16_rne(vv[j]);
        }
        __syncthreads();
        sh_ah[s_dst] = h;
        __syncthreads();
        t_idx += SB_OUT;
        if (t_idx < NTILES) {
            const float* src = s_srcbase + (size_t)t_idx * 2048;
            p0 = *(const float4*)src;
            p1 = *(const float4*)(src + 4);
        }

        f32x16 acc;
#pragma unroll
        for (int z = 0; z < 16; z++) acc[z] = 0.0f;
#pragma unroll
        for (int s = 0; s < 4; s++)
            acc = __builtin_amdgcn_mfma_f32_32x32x16_bf16(sh_ah[s * 64 + lane],
                                                          uh[s], acc, 0, 0, 0);

        const int ib4 = tb + 4 * (lane >> 5);
#pragma unroll
        for (int i = 0; i < 16; i += 4) {
            // acc element i=4q+j maps to item offset 8q+j (C/D layout, R7-verified)
            const int i0 = ib4 + 2 * i;          // 8*(i>>2) == 2*i for i%4==0
            u32 r0, r1, r2, r3;
            threefry_quad(rowbase_e + (u32)(i0 + 0), rowbase_e + (u32)(i0 + 1),
                          rowbase_e + (u32)(i0 + 2), rowbase_e + (u32)(i0 + 3),
                          r0, r1, r2, r3);
            float sA = acc[i], sB = acc[i + 1], sC = acc[i + 2], sD = acc[i + 3];
            sm = fmaxf(sm, fmaxf(fmaxf(sA, sB), fmaxf(sC, sD)));
            if (r0 >= BITS_RAW_T) {              // ~0.25%: push candidate
                int slot = atomicAdd(&ccnt[row], 1);
                if (slot < CCAP) cand[(size_t)row * CCAP + slot] =
                                     ((u64)r0 << 32) | (u32)(i0 + 0);
                else rowbad[row] = 1;
            }
            if (r1 >= BITS_RAW_T) {
                int slot = atomicAdd(&ccnt[row], 1);
                if (slot < CCAP) cand[(size_t)row * CCAP + slot] =
                                     ((u64)r1 << 32) | (u32)(i0 + 1);
                else rowbad[row] = 1;
            }
            if (r2 >= BITS_RAW_T) {
                int slot = atomicAdd(&ccnt[row], 1);
                if (slot < CCAP) cand[(size_t)row * CCAP + slot] =
                                     ((u64)r2 << 32) | (u32)(i0 + 2);
                else rowbad[row] = 1;
            }
            if (r3 >= BITS_RAW_T) {
                int slot = atomicAdd(&ccnt[row], 1);
                if (slot < CCAP) cand[(size_t)row * CCAP + slot] =
                                     ((u64)r3 << 32) | (u32)(i0 + 3);
                else rowbad[row] = 1;
            }
        }
    }

    sm = fmaxf(sm, __shfl_xor(sm, 32));
    if (lane < 32) atomicMax(&wsBm[row], order_map(sm));
}

// ---------------- K3: merge: exact candidate dots + certify (R10-validated)
// Cert: t1 > smb + E1 + 6.001 (every non-candidate has g <= 6.0).
__global__ void merge_kernel(const u32* __restrict__ wsBm, const float* __restrict__ wsAM4,
                             const float* __restrict__ unorm, const u64* __restrict__ cand,
                             const int* __restrict__ ccnt, const int* __restrict__ rowbad,
                             const float* __restrict__ uif, const float* __restrict__ A,
                             const int* __restrict__ need_replace,
                             u64* __restrict__ packed, int* __restrict__ rowlist,
                             int* __restrict__ cnt, float* __restrict__ out) {
    const int row = blockIdx.x, t = threadIdx.x;     // 64 threads = 1 wave
    __shared__ float Us[64];
    Us[t] = uif[row * 64 + t];
    __syncthreads();

    float am = 0.f;
    for (int i = t; i < AM4_N; i += 64) am = fmaxf(am, wsAM4[i]);
    const float smb = unpack_om(wsBm[row]);

    const int ncand = ccnt[row];
    const bool bad = (rowbad[row] != 0) || (ncand > CCAP);
    const int n = ncand < CCAP ? ncand : CCAP;

    u64 pk = 0ull;
    for (int j = t; j < n; j += 64) {
        u64 ent = cand[(size_t)row * CCAP + j];
        u32 item = (u32)ent;
        float g = gumbel_from_bits((u32)(ent >> 32));
        const float4* a4 = (const float4*)(A + (size_t)item * DDIM);
        float s0 = 0.f, s1 = 0.f;
#pragma unroll
        for (int k = 0; k < 16; k += 2) {     // R5-verified op order (exact)
            float4 x = a4[k];
            float4 y = a4[k + 1];
            s0 = fmaf(x.x, Us[4*k    ], s0);
            s0 = fmaf(x.y, Us[4*k + 1], s0);
            s0 = fmaf(x.z, Us[4*k + 2], s0);
            s0 = fmaf(x.w, Us[4*k + 3], s0);
            s1 = fmaf(y.x, Us[4*k + 4], s1);
            s1 = fmaf(y.y, Us[4*k + 5], s1);
            s1 = fmaf(y.z, Us[4*k + 6], s1);
            s1 = fmaf(y.w, Us[4*k + 7], s1);
        }
        float v = (s0 + s1) + g;
        u64 c = ((u64)order_map(v) << 32) | (u32)(~item);
        pk = (c > pk) ? c : pk;
    }
#pragma unroll
    for (int off = 1; off < 64; off <<= 1) {
        u64 o = __shfl_xor(pk, off);
        pk = (o > pk) ? o : pk;
        am = fmaxf(am, __shfl_xor(am, off));
    }
    // 1-term bf16 margin: |s_f32 - s_bf16| <= ~0.004*|a||u|; 2x headroom
    const float E1 = 8.0e-3f * unorm[row] * am + 1.0e-4f;
    const float v1 = unpack_val(pk);        // NaN when pk==0 -> cert false
    if (!bad && (v1 > smb + E1 + G_TE)) {
        const int idx = (int)(~(u32)(pk & 0xFFFFFFFFull));
        float fr = A[(size_t)idx * DDIM + t];
        out[OUT_FEAT + row * DDIM + t] = fr;
        int   item = need_replace[2 * row + 1];
        float fa   = A[(size_t)item * DDIM + t];
        float dot = fa * fr, na2 = fa * fa, nb2 = fr * fr;
#pragma unroll
        for (int o = 32; o >= 1; o >>= 1) {
            dot += __shfl_down(dot, o);
            na2 += __shfl_down(na2, o);
            nb2 += __shfl_down(nb2, o);
        }
        if (t == 0) {
            out[row] = (float)idx;
            float denom = fmaxf(sqrtf(na2) * sqrtf(nb2), 1e-6f);
            float sim = (dot / denom + 1.0f) * 0.5f;
            float d = sim - 0.5f;
            atomicAdd(&out[OUT_LOSS], d * d * (1.0f / 512.0f));
            atomicAdd(&out[OUT_MSIM], sim * (1.0f / 512.0f));
        }
    } else if (t == 0) {
        packed[row] = 0ull;
        rowlist[atomicAdd(cnt, 1)] = row;
    }
}

// ---------------- K4: exact f32 fallback (512 blocks); last block resolves -
__global__ void fallback_kernel(const float* __restrict__ A, const float* __restrict__ uif,
                                const int* __restrict__ rowlist, const int* __restrict__ cnt,
                                const int* __restrict__ need_replace,
                                u64* __restrict__ packed, int* __restrict__ done,
                                float* __restrict__ out) {
    __shared__ float Us[64];
    __shared__ int   sh_last;
    const int t  = threadIdx.x;          // 0..255
    const int xb = blockIdx.x;           // 0..63
    const int total = *cnt;
    const int iend = min((xb + 1) * FB_CHUNK, NITEMS);

    for (int li = blockIdx.y; li < total; li += FB_Y) {
        const int row = rowlist[li];
        __syncthreads();
        if (t < 64) Us[t] = uif[row * 64 + t];
        __syncthreads();
        u64 pk = 0ull;
        for (int item = xb * FB_CHUNK + t; item < iend; item += 256) {
            u32 rb  = threefry_0_42_xor((u32)row * (u32)NITEMS + (u32)item);
            float g = gumbel_from_bits(rb);
            const float4* a4 = (const float4*)(A + (size_t)item * DDIM);
            float s0 = 0.f, s1 = 0.f;
#pragma unroll
            for (int k = 0; k < 16; k += 2) {     // R5-verified op order
                float4 x = a4[k];
                float4 y = a4[k + 1];
                s0 = fmaf(x.x, Us[4*k    ], s0);
                s0 = fmaf(x.y, Us[4*k + 1], s0);
                s0 = fmaf(x.z, Us[4*k + 2], s0);
                s0 = fmaf(x.w, Us[4*k + 3], s0);
                s1 = fmaf(y.x, Us[4*k + 4], s1);
                s1 = fmaf(y.y, Us[4*k + 5], s1);
                s1 = fmaf(y.z, Us[4*k + 6], s1);
                s1 = fmaf(y.w, Us[4*k + 7], s1);
            }
            float v = (s0 + s1) + g;
            u64 c = ((u64)order_map(v) << 32) | (u32)(~(u32)item);
            pk = (c > pk) ? c : pk;
        }
#pragma unroll
        for (int off = 1; off < 64; off <<= 1) {
            u64 o = __shfl_xor(pk, off);
            pk = (o > pk) ? o : pk;
        }
        if ((t & 63) == 0) atomicMax(&packed[row], pk);
        __syncthreads();
        if (t == 0) {
            __threadfence();
            sh_last = (atomicAdd(&done[li], 1) == FB_X - 1) ? 1 : 0;
        }
        __syncthreads();
        if (sh_last && t < 64) {               // last contributor resolves row
            u64 fin = atomicMax(&packed[row], 0ull);   // coherent read
            const int idx = (int)(~(u32)(fin & 0xFFFFFFFFull));
            float fr = A[(size_t)idx * DDIM + t];
            out[OUT_FEAT + row * DDIM + t] = fr;
            int   item = need_replace[2 * row + 1];
            float fa   = A[(size_t)item * DDIM + t];
            float dot = fa * fr, na2 = fa * fa, nb2 = fr * fr;
#pragma unroll
            for (int o = 32; o >= 1; o >>= 1) {
                dot += __shfl_down(dot, o);
                na2 += __shfl_down(na2, o);
                nb2 += __shfl_down(nb2, o);
            }
            if (t == 0) {
                out[row] = (float)idx;
                float denom = fmaxf(sqrtf(na2) * sqrtf(nb2), 1e-6f);
                float sim = (dot / denom + 1.0f) * 0.5f;
                float d = sim - 0.5f;
                atomicAdd(&out[OUT_LOSS], d * d * (1.0f / 512.0f));
                atomicAdd(&out[OUT_MSIM], sim * (1.0f / 512.0f));
            }
        }
        __syncthreads();
    }
}

extern "C" void kernel_launch(void* const* d_in, const int* in_sizes, int n_in,
                              void* d_out, int out_size, void* d_ws, size_t ws_size,
                              hipStream_t stream) {
    (void)in_sizes; (void)n_in; (void)out_size; (void)ws_size;
    const int*   need_replace = (const int*)d_in[0];
    const float* UF           = (const float*)d_in[1];
    const float* A            = (const float*)d_in[2];
    const float* W            = (const float*)d_in[3];
    const float* bias         = (const float*)d_in[4];
    float* out = (float*)d_out;

    char* ws = (char*)d_ws;                              // ~1.73 MB total
    u64*   cand    = (u64*)  (ws);                       // 512*384*8 = 1572864
    float* uif     = (float*)(ws + 1572864);             // 131072
    u64*   packed  = (u64*)  (ws + 1703936);             // 4096
    float* unorm   = (float*)(ws + 1708032);             // 2048
    float* wsAM4   = (float*)(ws + 1710080);             // 6256
    int*   ccnt    = (int*)  (ws + 1716336);             // 2048
    int*   rowbad  = (int*)  (ws + 1718384);             // 2048
    int*   rowlist = (int*)  (ws + 1720432);             // 2048
    int*   cnt     = (int*)  (ws + 1722480);             // 4
    int*   done    = (int*)  (ws + 1722484);             // 2048
    u32*   wsBm    = (u32*)  (ws + 1724532);             // 2048

    prep_kernel<<<519, 256, 0, stream>>>(UF, W, bias, A, uif, unorm, wsAM4, cnt, done,
                                         ccnt, rowbad, wsBm, out);
    phase1_kernel<<<dim3(SB_OUT, 4), 256, 0, stream>>>(A, uif, wsBm, cand, ccnt, rowbad);
    merge_kernel<<<BROWS, 64, 0, stream>>>(wsBm, wsAM4, unorm, cand, ccnt, rowbad,
                                           uif, A, need_replace, packed, rowlist, cnt, out);
    fallback_kernel<<<dim3(FB_X, FB_Y), 256, 0, stream>>>(A, uif, rowlist, cnt,
                                                          need_replace, packed, done, out);
}